// Round 4
// baseline (103.770 us; speedup 1.0000x reference)
//
#include <hip/hip_runtime.h>

// DAG of 1x1 convs, fully fused, f16 MFMA.
// R10 = R9 (channel-split 4-wave blocks, 16 waves/CU) +
//  (a) earliest-retire schedule: node stores issue at k=3,6,11,15
//      (was 4,9,13,15) -> store drain overlaps remaining convs;
//  (b) nontemporal output stores (write-once data bypasses L2).
// Schedule (conv k -> weight widx / src buf / acc / retire):
//  k  : 0    1    2  3   4  5  6   7  8  9  10  11  12 13 14 15
//  w  : 0    1    2  3   4  5  6   7  8  9  11  10  12 13 14 15
//  src: 2    3    0  1   0  1  2   0  1  2  0   3   1  2  3  0
//  acc: A    A    A  A   A  A  A   A  A  A  B   A   B  B  B  B
//  ret: s0   s1   -  n2  -  -  n3  -  -  -  -   n4  -  -  -  n5
// buffers: s0->0, s1->1, n2->2 (was xin0), n3->3 (was xin1), n4->0 (s0 dead
// after k10's e9 read; pre-write barrier at k11).
// Per-node accumulation order == reference (n5: W11,W12,W13,W14,W15).
// k=0,1 non-swapped (D=W*X, vectorized LDS retire); k>=2 swapped (D=X*W^T,
// float4 global stores).

typedef _Float16 f16;
typedef _Float16 f16x8 __attribute__((ext_vector_type(8)));
typedef float    f32x4 __attribute__((ext_vector_type(4)));

#define RSH 72            // f16 per state row (144B: 16B-aligned, 2-way banks)
#define SB  (64 * RSH)    // 4608 f16 = 9216 B per state buffer (64 px)

__device__ __forceinline__ unsigned int pkrtz(float a, float b) {
    __fp16 h2 __attribute__((ext_vector_type(2))) = __builtin_amdgcn_cvt_pkrtz(a, b);
    return __builtin_bit_cast(unsigned int, h2);
}

// ---- kernel 1: W f32 [16][64][64] -> f16 fragment layout in ws ----
// flat u = ((k*2+kb)*4+q)*64 + row; ws[u*8 .. +7] = W[k][row][kb*32+q*8 .. +7]
__global__ __launch_bounds__(256) void wconv_kernel(
    const float* __restrict__ Wpre, const float* __restrict__ Wedge,
    f16* __restrict__ ws)
{
    const int u   = blockIdx.x * 256 + threadIdx.x;  // 0..8191
    const int k   = u >> 9;
    const int rem = u & 511;
    const int g   = rem >> 6;        // kb*4+q
    const int row = rem & 63;
    const float* src = ((k < 2) ? (Wpre + k * 4096) : (Wedge + (k - 2) * 4096))
                       + row * 64 + (g >> 2) * 32 + (g & 3) * 8;
    float4 v0 = ((const float4*)src)[0];
    float4 v1 = ((const float4*)src)[1];
    ((uint4*)ws)[u] = make_uint4(pkrtz(v0.x, v0.y), pkrtz(v0.z, v0.w),
                                 pkrtz(v1.x, v1.y), pkrtz(v1.z, v1.w));
}

// ---- kernel 2: the fused DAG ----
__global__ __launch_bounds__(256, 4) void dag_kernel(
    const float* __restrict__ x0, const float* __restrict__ x1,
    const f16* __restrict__ wf, float* __restrict__ out)
{
    __shared__ __align__(16) f16 lds[4 * SB];   // 36864 B -> 4 blocks/CU

    const int t    = threadIdx.x;   // 256 threads = 4 waves
    const int lane = t & 63;
    const int w    = t >> 6;        // wave id = 16-channel output slice
    const int pl   = lane & 15;
    const int q    = lane >> 4;

    const int blk = blockIdx.x;     // 1024 = 64 batches x 16 px-tiles (4/CU)
    const int b   = blk >> 4;
    const int hw0 = (blk & 15) * 64;

    const float* xg[2] = { x0 + b * 65536 + hw0, x1 + b * 65536 + hw0 };
    float* outg = out + b * 262144 + hw0;

    // lane W fragment base; frag(widx,kb) at + widx*4096 + kb*2048
    // (rows = out-ch w*16+pl, cols kb*32+q*8 .. +7)
    const f16* wl = wf + q * 512 + (w * 16 + pl) * 8;

    f16x8 wA[2][2];    // [parity][kb], double-buffered one conv ahead
    #pragma unroll
    for (int kb = 0; kb < 2; ++kb)
        wA[0][kb] = *(const f16x8*)(wl + kb * 2048);

    // ---- cooperative input staging -> f16 [p][c] buffers 2 (x0), 3 (x1) ----
    // wave w stages channel quarter w (16 ch) for all 64 px.
    {
        const int p = t & 63, h = t >> 6;
        #pragma unroll
        for (int inp = 0; inp < 2; ++inp) {
            const float* src = xg[inp] + (h * 16) * 1024 + p;
            unsigned int u[8];
            #pragma unroll
            for (int i = 0; i < 8; ++i)
                u[i] = pkrtz(src[(2 * i) * 1024], src[(2 * i + 1) * 1024]);
            uint4* dst = (uint4*)(lds + (2 + inp) * SB + p * RSH + h * 16);
            dst[0] = make_uint4(u[0], u[1], u[2], u[3]);
            dst[1] = make_uint4(u[4], u[5], u[6], u[7]);
        }
    }
    __syncthreads();

    f32x4 accA[4] = {};   // [j-tile] (4 x 16 px), 16-ch slice
    f32x4 accB[4] = {};

    const int widx_tab[16] = {0,1, 2, 3, 4, 5, 6, 7, 8, 9,11,10,12,13,14,15};
    const int src_tab [16] = {2,3, 0, 1, 0, 1, 2, 0, 1, 2, 0, 3, 1, 2, 3, 0};
    const int asel_tab[16] = {0,0, 0, 0, 0, 0, 0, 0, 0, 0, 1, 0, 1, 1, 1, 1};
    const int out_tab [16] = {-1,-1,-1, 0,-1,-1, 1,-1,-1,-1,-1, 2,-1,-1,-1, 3};
    const int dst_tab [16] = { 0, 1,-1, 2,-1,-1, 3,-1,-1,-1,-1, 0,-1,-1,-1,-1};

    #pragma unroll
    for (int k = 0; k < 16; ++k) {
        const int cur = k & 1, nxt = cur ^ 1;

        // prefetch W(k+1) slice (L1/L2-resident f16; 2 x 16B per lane)
        if (k < 15) {
            const f16* wn = wl + widx_tab[k + 1] * 4096;
            #pragma unroll
            for (int kb = 0; kb < 2; ++kb)
                wA[nxt][kb] = *(const f16x8*)(wn + kb * 2048);
        }

        // B fragments: all 64 px of the block ([p][c] LDS layout)
        const f16* S = lds + src_tab[k] * SB;
        f16x8 bf[4][2];
        #pragma unroll
        for (int jj = 0; jj < 4; ++jj)
            #pragma unroll
            for (int kb = 0; kb < 2; ++kb)
                bf[jj][kb] = *(const f16x8*)(S + (jj * 16 + pl) * RSH
                                               + kb * 32 + q * 8);

        const bool swp = (k >= 2);   // operand-swapped chains (X * W^T)

        auto step = [&](f32x4 (&acc)[4]) {
            #pragma unroll
            for (int jj = 0; jj < 4; ++jj)
                #pragma unroll
                for (int kb = 0; kb < 2; ++kb)
                    acc[jj] = swp
                        ? __builtin_amdgcn_mfma_f32_16x16x32_f16(
                              bf[jj][kb], wA[cur][kb], acc[jj], 0, 0, 0)
                        : __builtin_amdgcn_mfma_f32_16x16x32_f16(
                              wA[cur][kb], bf[jj][kb], acc[jj], 0, 0, 0);
        };
        auto retire = [&](f32x4 (&acc)[4]) {
            if (k == 11) __syncthreads();   // pre-write: all buf0(s0) reads done
            if (out_tab[k] >= 0) {   // swapped: lane holds 4 consecutive pixels
                #pragma unroll
                for (int jj = 0; jj < 4; ++jj)
                    __builtin_nontemporal_store(
                        acc[jj],
                        (f32x4*)(outg + (out_tab[k] * 64 + w * 16 + pl) * 1024
                                      + jj * 16 + q * 4));
            }
            if (dst_tab[k] >= 0) {   // relu'd state -> LDS ([p][c])
                f16* D = lds + dst_tab[k] * SB;
                if (!swp) {          // k=0,1: lane holds ch w*16+q*4+r, px jj*16+pl
                    #pragma unroll
                    for (int jj = 0; jj < 4; ++jj) {
                        unsigned int u0 = pkrtz(fmaxf(acc[jj][0], 0.f),
                                                fmaxf(acc[jj][1], 0.f));
                        unsigned int u1 = pkrtz(fmaxf(acc[jj][2], 0.f),
                                                fmaxf(acc[jj][3], 0.f));
                        *(uint2*)(D + (jj * 16 + pl) * RSH + w * 16 + q * 4) =
                            make_uint2(u0, u1);
                    }
                } else {             // swapped: px jj*16+q*4+r, ch w*16+pl
                    #pragma unroll
                    for (int jj = 0; jj < 4; ++jj)
                        #pragma unroll
                        for (int r = 0; r < 4; ++r)
                            D[(jj * 16 + q * 4 + r) * RSH + w * 16 + pl] =
                                (f16)fmaxf(acc[jj][r], 0.f);
                }
            }
            if (out_tab[k] >= 0 || dst_tab[k] >= 0) {
                #pragma unroll
                for (int jj = 0; jj < 4; ++jj)
                    acc[jj] = (f32x4){0.f, 0.f, 0.f, 0.f};
            }
            if (dst_tab[k] >= 0) __syncthreads();  // publish state to all waves
        };

        if (asel_tab[k] == 0) { step(accA); retire(accA); }
        else                  { step(accB); retire(accB); }
    }
}

extern "C" void kernel_launch(void* const* d_in, const int* in_sizes, int n_in,
                              void* d_out, int out_size, void* d_ws, size_t ws_size,
                              hipStream_t stream) {
    const float* x0    = (const float*)d_in[0];
    const float* x1    = (const float*)d_in[1];
    const float* Wpre  = (const float*)d_in[2];
    const float* Wedge = (const float*)d_in[3];
    float* outp        = (float*)d_out;
    f16*   wfrag       = (f16*)d_ws;          // 131072 B used

    wconv_kernel<<<dim3(32), dim3(256), 0, stream>>>(Wpre, Wedge, wfrag);
    dag_kernel<<<dim3(1024), dim3(256), 0, stream>>>(x0, x1, wfrag, outp);
}